// Round 1
// baseline (469.724 us; speedup 1.0000x reference)
//
#include <hip/hip_runtime.h>
#include <hip/hip_bf16.h>

// Problem constants (match reference)
constexpr int Bq  = 4;
constexpr int Nn  = 10000;
constexpr int Eq  = 170000;
constexpr int FIN = 256;
constexpr int Ff  = 128;
constexpr int Hh  = 4;
constexpr int M   = Bq * Nn;   // 40000 GEMM rows
constexpr int C   = Hh * Ff;   // 512 GEMM cols
constexpr float LEAKY = 0.2f;

// -------------------- K1: h = x @ W_mlp + b_mlp --------------------
// X: (M, 256) row-major. Output Hbuf: (M, 512) where col c = hi*128+f.
// W_mlp flat (H, FIN, F): element for (k, c) = W[(c>>7)*FIN*Ff + k*Ff + (c&127)].
// 64x64 tile, 256 threads, 4x4 micro-tile, BK=32.
__global__ __launch_bounds__(256) void gemm_kernel(
    const float* __restrict__ X, const float* __restrict__ W,
    const float* __restrict__ bias, float* __restrict__ Hout)
{
    const int bn = blockIdx.x;   // 0..7   (col tiles)
    const int bm = blockIdx.y;   // 0..624 (row tiles)
    const int tid = threadIdx.x;
    const int tx = tid & 15;     // col dir
    const int ty = tid >> 4;     // row dir

    __shared__ float As[32][65]; // [k][m], padded
    __shared__ float Bs[32][64]; // [k][n]

    const int row0 = bm * 64, col0 = bn * 64;
    const int hi = col0 >> 7;          // head for this whole tile (64 | 128)
    const int fb = col0 & 127;
    const float* Wt = W + (size_t)hi * FIN * Ff + fb; // Wt[k*128 + f], f in [0,64)

    float acc[4][4] = {};

    for (int k0 = 0; k0 < FIN; k0 += 32) {
        // Load A tile (64 rows x 32 k), transpose into As[k][m]
        {
            int r  = tid >> 3;        // 0..31
            int kq = (tid & 7) * 4;   // 0,4,..,28
            #pragma unroll
            for (int p = 0; p < 2; ++p) {
                int rr = r + p * 32;
                float4 v = *(const float4*)(X + (size_t)(row0 + rr) * FIN + k0 + kq);
                As[kq + 0][rr] = v.x; As[kq + 1][rr] = v.y;
                As[kq + 2][rr] = v.z; As[kq + 3][rr] = v.w;
            }
        }
        // Load B tile (32 k x 64 cols)
        {
            int kk = tid >> 4;        // 0..15
            int fq = (tid & 15) * 4;  // 0..60
            #pragma unroll
            for (int p = 0; p < 2; ++p) {
                int kr = kk + p * 16;
                float4 v = *(const float4*)(Wt + (size_t)(k0 + kr) * Ff + fq);
                *(float4*)&Bs[kr][fq] = v;
            }
        }
        __syncthreads();
        #pragma unroll
        for (int kk = 0; kk < 32; ++kk) {
            float a[4], b[4];
            #pragma unroll
            for (int i = 0; i < 4; ++i) a[i] = As[kk][ty * 4 + i];
            #pragma unroll
            for (int j = 0; j < 4; ++j) b[j] = Bs[kk][tx * 4 + j];
            #pragma unroll
            for (int i = 0; i < 4; ++i)
                #pragma unroll
                for (int j = 0; j < 4; ++j) acc[i][j] += a[i] * b[j];
        }
        __syncthreads();
    }

    // Epilogue: add bias (b_mlp flat (H,F) == column index), float4 stores
    #pragma unroll
    for (int i = 0; i < 4; ++i) {
        int r = row0 + ty * 4 + i;
        int c = col0 + tx * 4;
        float4 bv = *(const float4*)(bias + c);
        float4 o;
        o.x = acc[i][0] + bv.x; o.y = acc[i][1] + bv.y;
        o.z = acc[i][2] + bv.z; o.w = acc[i][3] + bv.w;
        *(float4*)(Hout + (size_t)r * C + c) = o;
    }
}

// -------------------- K2: p_src/p_dst from h[-1] --------------------
// One block (64 threads) per node; reduce 128-f dot per head.
__global__ __launch_bounds__(64) void attn_proj_kernel(
    const float* __restrict__ Hbuf, const float* __restrict__ Wattn,
    float* __restrict__ p_src, float* __restrict__ p_dst)
{
    int n = blockIdx.x;
    int t = threadIdx.x; // 0..63
    const float* hrow = Hbuf + (size_t)((Bq - 1) * Nn + n) * C;
    #pragma unroll
    for (int hi = 0; hi < Hh; ++hi) {
        float v1 = hrow[hi * Ff + t];
        float v2 = hrow[hi * Ff + t + 64];
        float as = v1 * Wattn[hi * 2 * Ff + t]       + v2 * Wattn[hi * 2 * Ff + t + 64];
        float ad = v1 * Wattn[hi * 2 * Ff + Ff + t]  + v2 * Wattn[hi * 2 * Ff + Ff + t + 64];
        #pragma unroll
        for (int off = 32; off; off >>= 1) {
            as += __shfl_down(as, off, 64);
            ad += __shfl_down(ad, off, 64);
        }
        if (t == 0) { p_src[hi * Nn + n] = as; p_dst[hi * Nn + n] = ad; }
    }
}

// -------------------- K3: row_start via binary search (src sorted) ----
__global__ void row_start_kernel(const int* __restrict__ src, int* __restrict__ row_start)
{
    int n = blockIdx.x * blockDim.x + threadIdx.x;
    if (n > Nn) return;
    int lo = 0, hi = Eq;
    while (lo < hi) { int mid = (lo + hi) >> 1; if (src[mid] < n) lo = mid + 1; else hi = mid; }
    row_start[n] = lo; // first edge with src >= n; row_start[Nn] == Eq
}

// -------------------- K4: per-edge scores e = exp(clip(lrelu(s))) -----
// eed layout: (E, 4) — float4 per edge.
__global__ void edge_score_kernel(
    const int* __restrict__ src, const int* __restrict__ dst,
    const float* __restrict__ p_src, const float* __restrict__ p_dst,
    float* __restrict__ eed)
{
    int e = blockIdx.x * blockDim.x + threadIdx.x;
    if (e >= Eq) return;
    int s = src[e], d = dst[e];
    #pragma unroll
    for (int hi = 0; hi < Hh; ++hi) {
        float sc = p_src[hi * Nn + s] + p_dst[hi * Nn + d];
        float lr = sc > 0.f ? sc : LEAKY * sc;
        lr = fminf(fmaxf(lr, -2.f), 2.f);
        eed[(size_t)e * 4 + hi] = __expf(lr);
    }
}

// -------------------- K5: denom[n][hi] = segment_sum(eed) -------------
__global__ __launch_bounds__(64) void denom_kernel(
    const float4* __restrict__ eed4, const int* __restrict__ row_start,
    float4* __restrict__ denom4)
{
    int n = blockIdx.x;
    int t = threadIdx.x;
    int e0 = row_start[n], e1 = row_start[n + 1];
    float4 acc = {0.f, 0.f, 0.f, 0.f};
    for (int e = e0 + t; e < e1; e += 64) {
        float4 v = eed4[e];
        acc.x += v.x; acc.y += v.y; acc.z += v.z; acc.w += v.w;
    }
    #pragma unroll
    for (int off = 32; off; off >>= 1) {
        acc.x += __shfl_down(acc.x, off, 64);
        acc.y += __shfl_down(acc.y, off, 64);
        acc.z += __shfl_down(acc.z, off, 64);
        acc.w += __shfl_down(acc.w, off, 64);
    }
    if (t == 0) denom4[n] = acc;
}

// -------------------- K6: aggregation (the gather) --------------------
// One block per source node n. 256 threads hold the full (B=4,H=4,F=128)
// = 2048-float output row as 2 float4 accumulators each.
__global__ __launch_bounds__(256) void aggregate_kernel(
    const float* __restrict__ Hbuf, const float4* __restrict__ eed4,
    const float4* __restrict__ denom4, const int* __restrict__ row_start,
    const int* __restrict__ dst, float* __restrict__ out)
{
    int n = blockIdx.x;
    int t = threadIdx.x;
    int e0 = row_start[n], e1 = row_start[n + 1];

    // lane -> (b, c) mapping for two float4 slots (l in [0,512), covers 2048 floats)
    int l0 = t, l1 = t + 256;
    int b0 = l0 >> 7, b1 = l1 >> 7;                 // batch
    int c0 = (l0 & 127) * 4, c1 = (l1 & 127) * 4;   // column in [0,512)
    int hi0 = (l0 >> 5) & 3, hi1 = (l1 >> 5) & 3;   // head = c>>7

    float4 dn = denom4[n];
    float inv[4];
    inv[0] = dn.x != 0.f ? 1.f / dn.x : 0.f;
    inv[1] = dn.y != 0.f ? 1.f / dn.y : 0.f;
    inv[2] = dn.z != 0.f ? 1.f / dn.z : 0.f;
    inv[3] = dn.w != 0.f ? 1.f / dn.w : 0.f;

    const float4* h4 = (const float4*)Hbuf;
    size_t base0 = (size_t)b0 * Nn * 128 + (c0 >> 2);
    size_t base1 = (size_t)b1 * Nn * 128 + (c1 >> 2);

    float4 acc0 = {0.f, 0.f, 0.f, 0.f};
    float4 acc1 = {0.f, 0.f, 0.f, 0.f};

    for (int e = e0; e < e1; ++e) {
        int d = dst[e];
        float4 ev = eed4[e];
        float w0 = (hi0 == 0 ? ev.x : hi0 == 1 ? ev.y : hi0 == 2 ? ev.z : ev.w) * inv[hi0];
        float w1 = (hi1 == 0 ? ev.x : hi1 == 1 ? ev.y : hi1 == 2 ? ev.z : ev.w) * inv[hi1];
        float4 v0 = h4[base0 + (size_t)d * 128];
        float4 v1 = h4[base1 + (size_t)d * 128];
        acc0.x += v0.x * w0; acc0.y += v0.y * w0; acc0.z += v0.z * w0; acc0.w += v0.w * w0;
        acc1.x += v1.x * w1; acc1.y += v1.y * w1; acc1.z += v1.z * w1; acc1.w += v1.w * w1;
    }

    float4* out4 = (float4*)out;
    out4[(size_t)(b0 * Nn + n) * 128 + (c0 >> 2)] = acc0;
    out4[(size_t)(b1 * Nn + n) * 128 + (c1 >> 2)] = acc1;
}

// -------------------- launch --------------------
extern "C" void kernel_launch(void* const* d_in, const int* in_sizes, int n_in,
                              void* d_out, int out_size, void* d_ws, size_t ws_size,
                              hipStream_t stream)
{
    const float* x      = (const float*)d_in[0]; // (B,N,256)
    const float* W_mlp  = (const float*)d_in[1]; // (H,256,128)
    const float* b_mlp  = (const float*)d_in[2]; // (H,128)
    const float* W_attn = (const float*)d_in[3]; // (H,256,1)
    const int*   src    = (const int*)d_in[4];   // (E,)
    const int*   dst    = (const int*)d_in[5];   // (E,)
    float* out = (float*)d_out;                  // (B,N,512)

    // workspace layout (floats)
    float* h      = (float*)d_ws;                    // M*C = 20,480,000
    float* eed    = h + (size_t)M * C;               // E*4 = 680,000
    float* p_src  = eed + (size_t)Eq * 4;            // H*N = 40,000
    float* p_dst  = p_src + (size_t)Hh * Nn;         // 40,000
    float* denom  = p_dst + (size_t)Hh * Nn;         // N*4 = 40,000
    int*   row_st = (int*)(denom + (size_t)Nn * 4);  // N+1

    // K1: GEMM h = x @ W_mlp + b
    dim3 g1(C / 64, M / 64);
    hipLaunchKernelGGL(gemm_kernel, g1, dim3(256), 0, stream, x, W_mlp, b_mlp, h);

    // K2: attention projections (uses batch B-1 slice of h)
    hipLaunchKernelGGL(attn_proj_kernel, dim3(Nn), dim3(64), 0, stream,
                       h, W_attn, p_src, p_dst);

    // K3: row_start via binary search
    hipLaunchKernelGGL(row_start_kernel, dim3((Nn + 256) / 256), dim3(256), 0, stream,
                       src, row_st);

    // K4: per-edge exp scores
    hipLaunchKernelGGL(edge_score_kernel, dim3((Eq + 255) / 256), dim3(256), 0, stream,
                       src, dst, p_src, p_dst, eed);

    // K5: per-node denominators
    hipLaunchKernelGGL(denom_kernel, dim3(Nn), dim3(64), 0, stream,
                       (const float4*)eed, row_st, (float4*)denom);

    // K6: weighted gather-aggregate
    hipLaunchKernelGGL(aggregate_kernel, dim3(Nn), dim3(256), 0, stream,
                       h, (const float4*)eed, (const float4*)denom, row_st, dst, out);
}

// Round 2
// 292.382 us; speedup vs baseline: 1.6065x; 1.6065x over previous
//
#include <hip/hip_runtime.h>
#include <hip/hip_bf16.h>

// Problem constants (match reference)
constexpr int Bq  = 4;
constexpr int Nn  = 10000;
constexpr int Eq  = 170000;
constexpr int FIN = 256;
constexpr int Ff  = 128;
constexpr int Hh  = 4;
constexpr int M   = Bq * Nn;   // 40000 GEMM rows
constexpr int C   = Hh * Ff;   // 512 GEMM cols
constexpr float LEAKY = 0.2f;

typedef short short8 __attribute__((ext_vector_type(8)));
typedef float f32x4  __attribute__((ext_vector_type(4)));

// float -> bf16 bits, round-to-nearest-even
static __device__ __forceinline__ unsigned short f2bf(float f) {
    unsigned int u = __float_as_uint(f);
    u = u + 0x7fffu + ((u >> 16) & 1u);
    return (unsigned short)(u >> 16);
}
static __device__ __forceinline__ float bf2f(unsigned short b) {
    return __uint_as_float(((unsigned int)b) << 16);
}

// -------------------- K0: Wt[c][k] = bf16(W[h][k][f]), c = h*128+f ------
__global__ void wprep_kernel(const float* __restrict__ W, unsigned short* __restrict__ Wt)
{
    int c = blockIdx.x;   // 0..511
    int k = threadIdx.x;  // 0..255
    float v = W[(size_t)(c >> 7) * FIN * Ff + (size_t)k * Ff + (c & 127)];
    Wt[(size_t)c * FIN + k] = f2bf(v);
}

// -------------------- K1: h = bf16( x @ W + b ), layout (n, b, c) -------
// Block: 64 rows x 512 cols (full C). 4 waves; wave w handles cols [w*128, w*128+128).
// mfma_f32_16x16x32_bf16 layouts (verified m89/m91):
//   A-frag: lane l holds A[m=l&15][k=quad*8+j]
//   B-frag: lane l holds B[k=quad*8+j][n=l&15]
//   C/D:    lane l reg r -> row m=quad*4+r, col n=l&15
__global__ __launch_bounds__(256) void gemm_mfma_kernel(
    const float* __restrict__ X, const unsigned short* __restrict__ Wt,
    const float* __restrict__ bias, unsigned short* __restrict__ Hb)
{
    __shared__ unsigned short As[64][264]; // [m][k], pad 256->264 (row 528B)

    const int row0 = blockIdx.x * 64;
    const int tid  = threadIdx.x;
    const int wave = tid >> 6, lane = tid & 63;
    const int quad = lane >> 4, ln = lane & 15;

    // ---- stage x (fp32) -> As (bf16), full K=256 ----
    {
        int m  = tid >> 2;       // 0..63
        int q4 = tid & 3;        // quarter of the row (64 floats)
        const float4* xr = (const float4*)(X + (size_t)(row0 + m) * FIN + q4 * 64);
        #pragma unroll
        for (int i = 0; i < 8; ++i) {
            float4 a = xr[2 * i], b = xr[2 * i + 1];
            short8 v;
            v[0] = (short)f2bf(a.x); v[1] = (short)f2bf(a.y);
            v[2] = (short)f2bf(a.z); v[3] = (short)f2bf(a.w);
            v[4] = (short)f2bf(b.x); v[5] = (short)f2bf(b.y);
            v[6] = (short)f2bf(b.z); v[7] = (short)f2bf(b.w);
            *(short8*)&As[m][q4 * 64 + i * 8] = v;
        }
    }
    __syncthreads();

    const int n0 = wave * 128;
    f32x4 acc[4][8];
    #pragma unroll
    for (int i = 0; i < 4; ++i)
        #pragma unroll
        for (int j = 0; j < 8; ++j) acc[i][j] = (f32x4){0.f, 0.f, 0.f, 0.f};

    #pragma unroll
    for (int ks = 0; ks < 8; ++ks) {
        short8 a[4];
        #pragma unroll
        for (int i = 0; i < 4; ++i)
            a[i] = *(const short8*)&As[i * 16 + ln][ks * 32 + quad * 8];
        #pragma unroll
        for (int j = 0; j < 8; ++j) {
            short8 b = *(const short8*)(Wt + (size_t)(n0 + j * 16 + ln) * FIN + ks * 32 + quad * 8);
            #pragma unroll
            for (int i = 0; i < 4; ++i)
                acc[i][j] = __builtin_amdgcn_mfma_f32_16x16x32_bf16(a[i], b, acc[i][j], 0, 0, 0);
        }
    }

    // ---- epilogue: +bias, ->bf16, LDS repack, coalesced 16B stores ----
    // output layout: Hb[((n*4)+b)*512 + c]
    #pragma unroll
    for (int r2 = 0; r2 < 2; ++r2) {
        __syncthreads();
        if ((wave >> 1) == r2) {
            int cbase = (wave & 1) * 136; // 136 shorts = 272B, 16B aligned
            #pragma unroll
            for (int j = 0; j < 8; ++j) {
                float bv = bias[n0 + j * 16 + ln];
                #pragma unroll
                for (int i = 0; i < 4; ++i)
                    #pragma unroll
                    for (int r = 0; r < 4; ++r)
                        As[i * 16 + quad * 4 + r][cbase + j * 16 + ln] =
                            f2bf(acc[i][j][r] + bv);
            }
        }
        __syncthreads();
        // cooperative store of c-range [r2*256, r2*256+256)
        int m   = tid >> 2;
        int sub = tid & 3;
        int mg  = row0 + m;
        int bb  = mg / Nn;
        int nn  = mg - bb * Nn;
        unsigned short* g = Hb + ((size_t)nn * Bq + bb) * C + r2 * 256 + sub * 64;
        const unsigned short* lsrc = &As[m][(sub < 2) ? sub * 64 : (136 + (sub - 2) * 64)];
        #pragma unroll
        for (int i = 0; i < 8; ++i)
            *(short8*)(g + i * 8) = *(const short8*)(lsrc + i * 8);
    }
}

// -------------------- K2: p_src/p_dst from h[-1] (b=3 slice) ------------
__global__ __launch_bounds__(64) void attn_proj_kernel(
    const unsigned short* __restrict__ Hb, const float* __restrict__ Wattn,
    float* __restrict__ p_src, float* __restrict__ p_dst)
{
    int n = blockIdx.x;
    int t = threadIdx.x; // 0..63
    const unsigned short* hrow = Hb + ((size_t)n * Bq + (Bq - 1)) * C;
    #pragma unroll
    for (int hi = 0; hi < Hh; ++hi) {
        float v1 = bf2f(hrow[hi * Ff + t]);
        float v2 = bf2f(hrow[hi * Ff + t + 64]);
        float as = v1 * Wattn[hi * 2 * Ff + t]      + v2 * Wattn[hi * 2 * Ff + t + 64];
        float ad = v1 * Wattn[hi * 2 * Ff + Ff + t] + v2 * Wattn[hi * 2 * Ff + Ff + t + 64];
        #pragma unroll
        for (int off = 32; off; off >>= 1) {
            as += __shfl_down(as, off, 64);
            ad += __shfl_down(ad, off, 64);
        }
        if (t == 0) { p_src[hi * Nn + n] = as; p_dst[hi * Nn + n] = ad; }
    }
}

// -------------------- K3: row_start via binary search (src sorted) ------
__global__ void row_start_kernel(const int* __restrict__ src, int* __restrict__ row_start)
{
    int n = blockIdx.x * blockDim.x + threadIdx.x;
    if (n > Nn) return;
    int lo = 0, hi = Eq;
    while (lo < hi) { int mid = (lo + hi) >> 1; if (src[mid] < n) lo = mid + 1; else hi = mid; }
    row_start[n] = lo;
}

// -------------------- K4: e = exp(clip(lrelu(s))) -----------------------
__global__ void edge_score_kernel(
    const int* __restrict__ src, const int* __restrict__ dst,
    const float* __restrict__ p_src, const float* __restrict__ p_dst,
    float* __restrict__ eed)
{
    int e = blockIdx.x * blockDim.x + threadIdx.x;
    if (e >= Eq) return;
    int s = src[e], d = dst[e];
    #pragma unroll
    for (int hi = 0; hi < Hh; ++hi) {
        float sc = p_src[hi * Nn + s] + p_dst[hi * Nn + d];
        float lr = sc > 0.f ? sc : LEAKY * sc;
        lr = fminf(fmaxf(lr, -2.f), 2.f);
        eed[(size_t)e * 4 + hi] = __expf(lr);
    }
}

// -------------------- K5: denom -----------------------------------------
__global__ __launch_bounds__(64) void denom_kernel(
    const float4* __restrict__ eed4, const int* __restrict__ row_start,
    float4* __restrict__ denom4)
{
    int n = blockIdx.x;
    int t = threadIdx.x;
    int e0 = row_start[n], e1 = row_start[n + 1];
    float4 acc = {0.f, 0.f, 0.f, 0.f};
    for (int e = e0 + t; e < e1; e += 64) {
        float4 v = eed4[e];
        acc.x += v.x; acc.y += v.y; acc.z += v.z; acc.w += v.w;
    }
    #pragma unroll
    for (int off = 32; off; off >>= 1) {
        acc.x += __shfl_down(acc.x, off, 64);
        acc.y += __shfl_down(acc.y, off, 64);
        acc.z += __shfl_down(acc.z, off, 64);
        acc.w += __shfl_down(acc.w, off, 64);
    }
    if (t == 0) denom4[n] = acc;
}

// -------------------- K6: gather-aggregate (bf16 h) ---------------------
// One block per src node. h row for node d = 2048 bf16 = 4KB contiguous.
// Thread t owns elements [t*8, t*8+8) of (b,hi,f) flat 2048.
__global__ __launch_bounds__(256) void aggregate_kernel(
    const unsigned short* __restrict__ Hb, const float4* __restrict__ eed4,
    const float4* __restrict__ denom4, const int* __restrict__ row_start,
    const int* __restrict__ dst, float* __restrict__ out)
{
    int n = blockIdx.x;
    int t = threadIdx.x;
    int e0 = row_start[n], e1 = row_start[n + 1];
    int hi = (t >> 4) & 3; // head of this thread's 8 elements

    float4 dn = denom4[n];
    float dv  = hi == 0 ? dn.x : hi == 1 ? dn.y : hi == 2 ? dn.z : dn.w;
    float inv = dv != 0.f ? 1.f / dv : 0.f;

    float acc[8];
    #pragma unroll
    for (int k = 0; k < 8; ++k) acc[k] = 0.f;

    int e = e0;
    for (; e + 1 < e1; e += 2) {
        int d0 = dst[e], d1 = dst[e + 1];
        float4 ev0 = eed4[e], ev1 = eed4[e + 1];
        float w0 = (hi == 0 ? ev0.x : hi == 1 ? ev0.y : hi == 2 ? ev0.z : ev0.w) * inv;
        float w1 = (hi == 0 ? ev1.x : hi == 1 ? ev1.y : hi == 2 ? ev1.z : ev1.w) * inv;
        short8 h0 = *(const short8*)(Hb + (size_t)d0 * 2048 + t * 8);
        short8 h1 = *(const short8*)(Hb + (size_t)d1 * 2048 + t * 8);
        #pragma unroll
        for (int k = 0; k < 8; ++k) acc[k] += bf2f((unsigned short)h0[k]) * w0;
        #pragma unroll
        for (int k = 0; k < 8; ++k) acc[k] += bf2f((unsigned short)h1[k]) * w1;
    }
    if (e < e1) {
        int d0 = dst[e];
        float4 ev0 = eed4[e];
        float w0 = (hi == 0 ? ev0.x : hi == 1 ? ev0.y : hi == 2 ? ev0.z : ev0.w) * inv;
        short8 h0 = *(const short8*)(Hb + (size_t)d0 * 2048 + t * 8);
        #pragma unroll
        for (int k = 0; k < 8; ++k) acc[k] += bf2f((unsigned short)h0[k]) * w0;
    }

    // out layout (b, n, c): b = t>>6, c = (t&63)*8
    float* g = out + ((size_t)(t >> 6) * Nn + n) * C + (t & 63) * 8;
    float4 o0 = {acc[0], acc[1], acc[2], acc[3]};
    float4 o1 = {acc[4], acc[5], acc[6], acc[7]};
    *(float4*)g       = o0;
    *(float4*)(g + 4) = o1;
}

// -------------------- launch --------------------
extern "C" void kernel_launch(void* const* d_in, const int* in_sizes, int n_in,
                              void* d_out, int out_size, void* d_ws, size_t ws_size,
                              hipStream_t stream)
{
    const float* x      = (const float*)d_in[0]; // (B,N,256)
    const float* W_mlp  = (const float*)d_in[1]; // (H,256,128)
    const float* b_mlp  = (const float*)d_in[2]; // (H,128)
    const float* W_attn = (const float*)d_in[3]; // (H,256,1)
    const int*   src    = (const int*)d_in[4];   // (E,)
    const int*   dst    = (const int*)d_in[5];   // (E,)
    float* out = (float*)d_out;                  // (B,N,512)

    // workspace layout
    unsigned short* h  = (unsigned short*)d_ws;        // M*C bf16 = 40.96 MB
    unsigned short* Wt = h + (size_t)M * C;            // 512*256 bf16
    float* eed   = (float*)(Wt + (size_t)C * FIN);     // E*4 floats
    float* p_src = eed + (size_t)Eq * 4;
    float* p_dst = p_src + (size_t)Hh * Nn;
    float* denom = p_dst + (size_t)Hh * Nn;
    int*   row_st = (int*)(denom + (size_t)Nn * 4);

    hipLaunchKernelGGL(wprep_kernel, dim3(C), dim3(FIN), 0, stream, W_mlp, Wt);

    hipLaunchKernelGGL(gemm_mfma_kernel, dim3(M / 64), dim3(256), 0, stream,
                       x, Wt, b_mlp, h);

    hipLaunchKernelGGL(attn_proj_kernel, dim3(Nn), dim3(64), 0, stream,
                       h, W_attn, p_src, p_dst);

    hipLaunchKernelGGL(row_start_kernel, dim3((Nn + 256) / 256), dim3(256), 0, stream,
                       src, row_st);

    hipLaunchKernelGGL(edge_score_kernel, dim3((Eq + 255) / 256), dim3(256), 0, stream,
                       src, dst, p_src, p_dst, eed);

    hipLaunchKernelGGL(denom_kernel, dim3(Nn), dim3(64), 0, stream,
                       (const float4*)eed, row_st, (float4*)denom);

    hipLaunchKernelGGL(aggregate_kernel, dim3(Nn), dim3(256), 0, stream,
                       h, (const float4*)eed, (const float4*)denom, row_st, dst, out);
}